// Round 11
// baseline (322.601 us; speedup 1.0000x reference)
//
#include <hip/hip_runtime.h>

#define B_  4
#define LQ  1024
#define LC  2047
#define LK  2048
#define F_  2048
#define H_  16
#define DH  128
#define NT  (LK / 64)

typedef __attribute__((ext_vector_type(4))) float f32x4;
typedef __attribute__((ext_vector_type(8))) __bf16 bf16x8;
typedef __attribute__((ext_vector_type(8))) unsigned short u16x8;

#define GLD16(gp, lp)                                                          \
  __builtin_amdgcn_global_load_lds(                                            \
      (const __attribute__((address_space(1))) void*)(gp),                     \
      (__attribute__((address_space(3))) void*)(lp), 16, 0, 0)

__device__ __forceinline__ unsigned short f2bf(float f) {
  unsigned u = __float_as_uint(f);
  u += 0x7FFFu + ((u >> 16) & 1u);
  return (unsigned short)(u >> 16);
}
__device__ __forceinline__ unsigned short f2bf_trunc(float f) {
  return (unsigned short)(__float_as_uint(f) >> 16);
}
__device__ __forceinline__ float bf2f(unsigned short u) {
  return __uint_as_float((unsigned)u << 16);
}

// ---------------- cos/sin table: [pos 0..2047][j 0..63] ----------------
__global__ void k_tables(float* __restrict__ cost, float* __restrict__ sint) {
  int idx = blockIdx.x * 256 + threadIdx.x;   // 2048*64 entries
  int pos = idx >> 6, j = idx & 63;
  float theta = powf(1000.0f, -(float)j / 64.0f);
  float a = (float)pos * theta;
  cost[idx] = cosf(a);
  sint[idx] = sinf(a);
}

// ------- key_new/val_new partials: grid (8 colblk, 2 kv, 8 kchunk) ------
__global__ void k_gemv_part(const float* __restrict__ kv, const float* __restrict__ Wk,
                            const float* __restrict__ Wv, float* __restrict__ part) {
  __shared__ float kvs[4][256];
  int tid = threadIdx.x, z = blockIdx.z;
#pragma unroll
  for (int b = 0; b < 4; ++b) kvs[b][tid] = kv[b * F_ + z * 256 + tid];
  __syncthreads();
  const float* W = blockIdx.y ? Wv : Wk;
  int col = blockIdx.x * 256 + tid;
  float a0 = 0.f, a1 = 0.f, a2 = 0.f, a3 = 0.f;
  for (int k = 0; k < 256; ++k) {
    float w = W[(size_t)(z * 256 + k) * F_ + col];
    a0 = fmaf(kvs[0][k], w, a0);
    a1 = fmaf(kvs[1][k], w, a1);
    a2 = fmaf(kvs[2][k], w, a2);
    a3 = fmaf(kvs[3][k], w, a3);
  }
  float* o = part + (size_t)(blockIdx.y * 8 + z) * 8192;
  o[col] = a0; o[2048 + col] = a1; o[4096 + col] = a2; o[6144 + col] = a3;
}

__global__ void k_gemv_reduce(const float* __restrict__ part, float* __restrict__ knew,
                              float* __restrict__ vnew) {
  int t = blockIdx.x * 256 + threadIdx.x;   // 16384
  int y = t >> 13, idx = t & 8191;
  float s = 0.f;
#pragma unroll
  for (int z = 0; z < 8; ++z) s += part[(size_t)(y * 8 + z) * 8192 + idx];
  (y ? vnew : knew)[idx] = s;
}

// ------- fused: cache copy-out + append, build RoPE'd K (bf16) + V (bf16)
__global__ void k_prep_kv(const float* __restrict__ cache, const float* __restrict__ knew,
                          const float* __restrict__ vnew, const float* __restrict__ cost,
                          const float* __restrict__ sint, float* __restrict__ cache_out,
                          unsigned short* __restrict__ Kr, unsigned short* __restrict__ Vb) {
  int t = blockIdx.x * 256 + threadIdx.x;   // 4*2048*16*64 = 2^23 threads
  int j = t & 63, h = (t >> 6) & 15, pos = (t >> 10) & 2047, b = t >> 21;
  int f = h * DH + j;
  float k1, v1, k2, v2;
  if (pos < LC) {
    const float* p = cache + ((size_t)(b * LC + pos) * F_ + f) * 2;
    float2 x = *(const float2*)p;
    float2 y = *(const float2*)(p + 128);     // f + 64
    k1 = x.x; v1 = x.y; k2 = y.x; v2 = y.y;
  } else {
    k1 = knew[b * F_ + f];      v1 = vnew[b * F_ + f];
    k2 = knew[b * F_ + f + 64]; v2 = vnew[b * F_ + f + 64];
  }
  float* o = cache_out + ((size_t)(b * LK + pos) * F_ + f) * 2;
  *(float2*)o = make_float2(k1, v1);
  *(float2*)(o + 128) = make_float2(k2, v2);
  float c = cost[pos * 64 + j], s = sint[pos * 64 + j];
  size_t kb = ((size_t)(b * H_ + h) * LK + pos) * DH + j;
  Kr[kb]      = f2bf(k1 * c - k2 * s);
  Kr[kb + 64] = f2bf(k2 * c + k1 * s);
  Vb[kb]      = f2bf(v1);
  Vb[kb + 64] = f2bf(v2);
}

// ------- W [K][N] f32 -> Wt [N][K] bf16, both weights in one launch -----
__global__ void k_transpose_w(const float* __restrict__ Wq, const float* __restrict__ Wo,
                              unsigned short* __restrict__ WqT, unsigned short* __restrict__ WoT) {
  __shared__ float tile[32][33];
  const float* W = blockIdx.z ? Wo : Wq;
  unsigned short* Wt = blockIdx.z ? WoT : WqT;
  int n0 = blockIdx.x * 32, k0 = blockIdx.y * 32;
  int tx = threadIdx.x & 31, ty = threadIdx.x >> 5;
#pragma unroll
  for (int p = 0; p < 4; ++p)
    tile[ty + p * 8][tx] = W[(size_t)(k0 + ty + p * 8) * F_ + n0 + tx];
  __syncthreads();
#pragma unroll
  for (int p = 0; p < 4; ++p)
    Wt[(size_t)(n0 + ty + p * 8) * F_ + k0 + tx] = f2bf(tile[tx][ty + p * 8]);
}

// ---------------- f32 -> bf16 elementwise (q) ---------------------------
__global__ void k_q_bf16(const float* __restrict__ x, unsigned short* __restrict__ y) {
  int t = blockIdx.x * 256 + threadIdx.x;
  float4 v = ((const float4*)x)[t];
  ushort4 o;
  o.x = f2bf(v.x); o.y = f2bf(v.y); o.z = f2bf(v.z); o.w = f2bf(v.w);
  ((ushort4*)y)[t] = o;
}

// --------- bf16 MFMA GEMM (m97 structure): C = A[M][K] * Bt[N][K]^T -----
// MODE 0: plain f32 C.  MODE 2: fused RoPE epilogue (N-tile == head dim):
// exchange accumulator halves via LDS, apply rotation + log2e/sqrt(dh)
// scale, write Qro[(b,h,qi,d)] bf16 directly.
template <int MODE>
__launch_bounds__(256)
__global__ void k_gemm(const unsigned short* __restrict__ A, const unsigned short* __restrict__ Bt,
                       void* __restrict__ Cv, const float* __restrict__ cost,
                       const float* __restrict__ sint, int M, int N, int K) {
  __shared__ __align__(16) unsigned short SMEM[16640];   // As|Bs (16KB); reused as X (33KB)
  unsigned short* As = SMEM;
  unsigned short* Bs = SMEM + 4096;
  int tid = threadIdx.x, wid = tid >> 6, l = tid & 63;
  int wm = wid >> 1, wn = wid & 1;
  int lr = l & 15, lg = l >> 4;
  int m0 = blockIdx.y * 128, n0 = blockIdx.x * 128;
  int row0 = tid >> 2, ch = tid & 3;
  const unsigned short* ga0 = A  + (size_t)(m0 + row0) * K + ch * 8;
  const unsigned short* ga1 = A  + (size_t)(m0 + row0 + 64) * K + ch * 8;
  const unsigned short* gb0 = Bt + (size_t)(n0 + row0) * K + ch * 8;
  const unsigned short* gb1 = Bt + (size_t)(n0 + row0 + 64) * K + ch * 8;
  f32x4 acc[4][4];
#pragma unroll
  for (int i = 0; i < 4; ++i)
#pragma unroll
    for (int j = 0; j < 4; ++j) acc[i][j] = (f32x4){0.f, 0.f, 0.f, 0.f};

  for (int kt = 0; kt < K; kt += 32) {
    __syncthreads();
    GLD16(ga0 + kt, As + tid * 8);
    GLD16(ga1 + kt, As + (tid + 256) * 8);
    GLD16(gb0 + kt, Bs + tid * 8);
    GLD16(gb1 + kt, Bs + (tid + 256) * 8);
    __syncthreads();
    bf16x8 af[4], bfr[4];
#pragma unroll
    for (int i = 0; i < 4; ++i) {
      af[i]  = *(const bf16x8*)&As[(wm * 64 + i * 16 + lr) * 32 + lg * 8];
      bfr[i] = *(const bf16x8*)&Bs[(wn * 64 + i * 16 + lr) * 32 + lg * 8];
    }
    __builtin_amdgcn_s_setprio(1);
#pragma unroll
    for (int mi = 0; mi < 4; ++mi)
#pragma unroll
      for (int ni = 0; ni < 4; ++ni)
        acc[mi][ni] = __builtin_amdgcn_mfma_f32_16x16x32_bf16(af[mi], bfr[ni], acc[mi][ni], 0, 0, 0);
    __builtin_amdgcn_s_setprio(0);
  }

  if (MODE == 0) {
#pragma unroll
    for (int mi = 0; mi < 4; ++mi)
#pragma unroll
      for (int ni = 0; ni < 4; ++ni) {
        int row = m0 + wm * 64 + mi * 16 + lg * 4;
        int col = n0 + wn * 64 + ni * 16 + lr;
#pragma unroll
        for (int r = 0; r < 4; ++r)
          ((float*)Cv)[(size_t)(row + r) * N + col] = acc[mi][ni][r];
      }
  } else {
    // ---- fused RoPE epilogue ----
    unsigned short* X = SMEM;                 // [128][130] bf16 exchange tile
    __syncthreads();                          // all waves done with As/Bs
#pragma unroll
    for (int mi = 0; mi < 4; ++mi)
#pragma unroll
      for (int ni = 0; ni < 4; ++ni) {
        int lrow = wm * 64 + mi * 16 + lg * 4;
        int col = wn * 64 + ni * 16 + lr;
#pragma unroll
        for (int r = 0; r < 4; ++r)
          X[(lrow + r) * 130 + col] = f2bf(acc[mi][ni][r]);
      }
    __syncthreads();
    int h = blockIdx.x;
    const float scale = 0.12751743343788055f;  // (1/sqrt(128)) * log2(e)
    unsigned short* Q = (unsigned short*)Cv;
#pragma unroll
    for (int mi = 0; mi < 4; ++mi) {
      int lrow0 = wm * 64 + mi * 16 + lg * 4;
#pragma unroll
      for (int r = 0; r < 4; ++r) {
        int lrow = lrow0 + r;
        int grow = m0 + lrow;
        int qi = grow & 1023, b = grow >> 10;
        size_t obase = ((size_t)(b * H_ + h) * LQ + qi) * DH;
#pragma unroll
        for (int ni = 0; ni < 4; ++ni) {
          int col = wn * 64 + ni * 16 + lr;
          int jj = col & 63;
          float c = cost[qi * 64 + jj], s = sint[qi * 64 + jj];
          float a = acc[mi][ni][r];
          float a2 = bf2f(X[lrow * 130 + (col ^ 64)]);
          float o = (col < 64) ? (a * c - a2 * s) : (a * c + a2 * s);
          Q[obase + col] = f2bf(o * scale);
        }
      }
    }
  }
}

// --- flash attention: 4 waves x 32 q-rows, BK=64, rotated pipeline ------
// All prefetch (K via GLD16, V via regs) issued one full tile ahead;
// vmcnt(0) at iter top is then free. ds_write V(t) happens right after
// barrier A, so barrier B's wait covers only short LDS writes.
__launch_bounds__(256, 2)
__global__ void k_attn(const unsigned short* __restrict__ Qr, const unsigned short* __restrict__ Kr,
                       const unsigned short* __restrict__ Vb, unsigned short* __restrict__ Oo) {
  __shared__ __align__(16) unsigned short KsB[2][64 * 128]; // linear, chunk-swizzled
  __shared__ __align__(16) unsigned short Vt[128][72];      // V transposed+swizzled [d][key]
  __shared__ __align__(16) unsigned short Pb[4][32][72];    // per-wave P [q][key^(8*lg)]
  int tid = threadIdx.x, wid = tid >> 6, l = tid & 63;
  int lr = l & 15, lg = l >> 4;
  int bh = blockIdx.x, q0 = blockIdx.y * 128 + wid * 32;    // grid (64,8): same-bh -> same XCD
  const unsigned short* Qb = Qr + ((size_t)bh * LQ + q0) * DH;
  const unsigned short* Kb = Kr + (size_t)bh * LK * DH;
  const unsigned short* Vp = Vb + (size_t)bh * LK * DH;

  bf16x8 qf[2][4];
#pragma unroll
  for (int s = 0; s < 2; ++s)
#pragma unroll
    for (int c = 0; c < 4; ++c)
      qf[s][c] = *(const bf16x8*)(Qb + (size_t)(s * 16 + lr) * DH + c * 32 + lg * 8);

  // K staging: 4 chunks/thread; stored chunk c of row holds global chunk c^(row&15)
  int gkoff[4], lkoff[4];
#pragma unroll
  for (int p = 0; p < 4; ++p) {
    int g = tid + p * 256, row = g >> 4, cc = g & 15;
    gkoff[p] = row * DH + (cc ^ (row & 15)) * 8;
    lkoff[p] = g * 8;
  }

  f32x4 oacc[2][8];
#pragma unroll
  for (int s = 0; s < 2; ++s)
#pragma unroll
    for (int i = 0; i < 8; ++i) oacc[s][i] = (f32x4){0.f, 0.f, 0.f, 0.f};
  float mrun[2][4] = {{-1e30f, -1e30f, -1e30f, -1e30f}, {-1e30f, -1e30f, -1e30f, -1e30f}};
  float lpart[2][4] = {{0.f, 0.f, 0.f, 0.f}, {0.f, 0.f, 0.f, 0.f}};

  int kp = tid >> 4, cg = tid & 15;

  // prologue: K(0) -> buf0; V(0) -> regs
#pragma unroll
  for (int p = 0; p < 4; ++p) GLD16(Kb + gkoff[p], &KsB[0][lkoff[p]]);
  const unsigned short* vs0 = Vp + (size_t)(kp * 2) * DH + cg * 8;
  u16x8 v00 = *(const u16x8*)(vs0);
  u16x8 v01 = *(const u16x8*)(vs0 + DH);
  u16x8 v10 = *(const u16x8*)(vs0 + 32 * DH);
  u16x8 v11 = *(const u16x8*)(vs0 + 33 * DH);

  for (int kt = 0; kt < NT; ++kt) {
    int cur = kt & 1;
    // everything needed this tile was issued a full tile ago -> free wait
    asm volatile("s_waitcnt vmcnt(0)" ::: "memory");
    __builtin_amdgcn_sched_barrier(0);
    __builtin_amdgcn_s_barrier();      // A: all waves done reading prev tile
    __builtin_amdgcn_sched_barrier(0);

    // V(t) ds_writes (packed u32, swizzled; conflict-free)
#pragma unroll
    for (int pp = 0; pp < 2; ++pp) {
      int kpp = kp + pp * 16;
      int kks = kpp ^ ((cg & 7) << 2);
      u16x8 a = pp ? v10 : v00, b2 = pp ? v11 : v01;
#pragma unroll
      for (int e = 0; e < 8; ++e) {
        unsigned pack = (unsigned)a[e] | ((unsigned)b2[e] << 16);
        *(unsigned*)&Vt[cg * 8 + e][kks * 2] = pack;
      }
    }
    // prefetch K(t+1) into alt buffer (dummy tile-0 prefetch on last iter)
    {
      const unsigned short* Kn = Kb + (size_t)((kt + 1 < NT) ? (kt + 1) * 64 * DH : 0);
#pragma unroll
      for (int p = 0; p < 4; ++p) GLD16(Kn + gkoff[p], &KsB[cur ^ 1][lkoff[p]]);
    }
    // prefetch V(t+1) into regs (dummy re-read of t on last iter)
    {
      int tn = (kt + 1 < NT) ? kt + 1 : kt;
      const unsigned short* vn = Vp + (size_t)(tn * 64 + kp * 2) * DH + cg * 8;
      v00 = *(const u16x8*)(vn);
      v01 = *(const u16x8*)(vn + DH);
      v10 = *(const u16x8*)(vn + 32 * DH);
      v11 = *(const u16x8*)(vn + 33 * DH);
    }
    // own Vt writes done; cross-wave visibility via barrier B
    asm volatile("s_waitcnt lgkmcnt(0)" ::: "memory");
    __builtin_amdgcn_sched_barrier(0);
    __builtin_amdgcn_s_barrier();      // B: K(t) + Vt(t) ready for all
    __builtin_amdgcn_sched_barrier(0);

    // S = Q K^T : K fragment loaded once, used by both subtiles
    const unsigned short* Kcur = KsB[cur];
    f32x4 sf[2][4];
    __builtin_amdgcn_s_setprio(1);
#pragma unroll
    for (int ct = 0; ct < 4; ++ct) {
      f32x4 s0 = (f32x4){0.f, 0.f, 0.f, 0.f};
      f32x4 s1 = (f32x4){0.f, 0.f, 0.f, 0.f};
#pragma unroll
      for (int ck = 0; ck < 4; ++ck) {
        bf16x8 kf = *(const bf16x8*)&Kcur[(ct * 16 + lr) * 128 + (((ck * 4 + lg) ^ lr) << 3)];
        s0 = __builtin_amdgcn_mfma_f32_16x16x32_bf16(qf[0][ck], kf, s0, 0, 0, 0);
        s1 = __builtin_amdgcn_mfma_f32_16x16x32_bf16(qf[1][ck], kf, s1, 0, 0, 0);
      }
      sf[0][ct] = s0; sf[1][ct] = s1;
    }
    __builtin_amdgcn_s_setprio(0);

    // defer-max online softmax (both subtiles share the skip test)
    float pmax[2][4];
    bool allok = true;
#pragma unroll
    for (int s = 0; s < 2; ++s)
#pragma unroll
      for (int r = 0; r < 4; ++r) {
        pmax[s][r] = fmaxf(fmaxf(sf[s][0][r], sf[s][1][r]), fmaxf(sf[s][2][r], sf[s][3][r]));
        allok = allok && (pmax[s][r] - mrun[s][r] <= 8.0f);
      }
    if (!__all(allok)) {
#pragma unroll
      for (int s = 0; s < 2; ++s)
#pragma unroll
        for (int r = 0; r < 4; ++r) {
          float m = pmax[s][r];
#pragma unroll
          for (int off = 1; off < 16; off <<= 1) m = fmaxf(m, __shfl_xor(m, off));
          float mnew = fmaxf(mrun[s][r], m);
          float scl = exp2f(mrun[s][r] - mnew);
          lpart[s][r] *= scl;
#pragma unroll
          for (int dt = 0; dt < 8; ++dt) oacc[s][dt][r] *= scl;
          mrun[s][r] = mnew;
        }
    }
#pragma unroll
    for (int s = 0; s < 2; ++s)
#pragma unroll
      for (int r = 0; r < 4; ++r) {
#pragma unroll
        for (int ct = 0; ct < 4; ++ct) {
          float pe = exp2f(sf[s][ct][r] - mrun[s][r]);
          Pb[wid][s * 16 + lg * 4 + r][(ct * 16 + lr) ^ (lg << 3)] = f2bf_trunc(pe);
          lpart[s][r] += pe;
        }
      }

    // own Pb writes committed (wave-private -> no barrier needed)
    asm volatile("s_waitcnt lgkmcnt(0)" ::: "memory");
    __builtin_amdgcn_sched_barrier(0);

    // O += P V : V fragment loaded once, used by both subtiles
    int psw = (lg ^ (lr >> 2)) << 3;
    bf16x8 pf00 = *(const bf16x8*)&Pb[wid][lr][psw];
    bf16x8 pf01 = *(const bf16x8*)&Pb[wid][lr][32 + psw];
    bf16x8 pf10 = *(const bf16x8*)&Pb[wid][16 + lr][psw];
    bf16x8 pf11 = *(const bf16x8*)&Pb[wid][16 + lr][32 + psw];
    __builtin_amdgcn_s_setprio(1);
#pragma unroll
    for (int dt = 0; dt < 8; ++dt) {
      int d = dt * 16 + lr;
      int x = (d >> 3) & 7;
      bf16x8 v0 = *(const bf16x8*)&Vt[d][(lg ^ x) << 3];
      bf16x8 v1 = *(const bf16x8*)&Vt[d][((4 + lg) ^ x) << 3];
      oacc[0][dt] = __builtin_amdgcn_mfma_f32_16x16x32_bf16(pf00, v0, oacc[0][dt], 0, 0, 0);
      oacc[0][dt] = __builtin_amdgcn_mfma_f32_16x16x32_bf16(pf01, v1, oacc[0][dt], 0, 0, 0);
      oacc[1][dt] = __builtin_amdgcn_mfma_f32_16x16x32_bf16(pf10, v0, oacc[1][dt], 0, 0, 0);
      oacc[1][dt] = __builtin_amdgcn_mfma_f32_16x16x32_bf16(pf11, v1, oacc[1][dt], 0, 0, 0);
    }
    __builtin_amdgcn_s_setprio(0);
  }

  int b = bh >> 4, h = bh & 15;
#pragma unroll
  for (int s = 0; s < 2; ++s)
#pragma unroll
    for (int r = 0; r < 4; ++r) {
      float sum = lpart[s][r];
#pragma unroll
      for (int off = 1; off < 16; off <<= 1) sum += __shfl_xor(sum, off);
      float inv = 1.0f / sum;
      int qrow = q0 + s * 16 + lg * 4 + r;
      size_t base = ((size_t)(b * LQ + qrow)) * F_ + h * DH;
#pragma unroll
      for (int dt = 0; dt < 8; ++dt)
        Oo[base + dt * 16 + lr] = f2bf(oacc[s][dt][r] * inv);
    }
}

extern "C" void kernel_launch(void* const* d_in, const int* in_sizes, int n_in,
                              void* d_out, int out_size, void* d_ws, size_t ws_size,
                              hipStream_t stream) {
  const float* kv    = (const float*)d_in[0];
  const float* q     = (const float*)d_in[1];
  const float* cache = (const float*)d_in[2];
  const float* Wq    = (const float*)d_in[3];
  const float* Wk    = (const float*)d_in[4];
  const float* Wv    = (const float*)d_in[5];
  const float* Wo    = (const float*)d_in[6];

  float* logits    = (float*)d_out;
  float* cache_out = logits + (size_t)B_ * LQ * F_;

  char* ws = (char*)d_ws;
  float* cost          = (float*)(ws);                       // 512 KB
  float* sint          = (float*)(ws + 524288);              // 512 KB
  float* knew          = (float*)(ws + 1048576);             // 32 KB
  float* vnew          = (float*)(ws + 1081344);             // 32 KB
  float* gpart         = (float*)(ws + 1114112);             // 512 KB
  unsigned short* WqT  = (unsigned short*)(ws + 1638400);    // 8 MB
  unsigned short* WoT  = (unsigned short*)(ws + 10027008);   // 8 MB
  unsigned short* qbf  = (unsigned short*)(ws + 18415616);   // 16 MB
  unsigned short* Qro  = (unsigned short*)(ws + 35192832);   // 16 MB
  unsigned short* Kro  = (unsigned short*)(ws + 51970048);   // 32 MB
  unsigned short* Vbf  = (unsigned short*)(ws + 85524480);   // 32 MB
  unsigned short* attno = (unsigned short*)(ws + 127467520); // 16 MB

  k_tables<<<dim3(512), dim3(256), 0, stream>>>(cost, sint);
  k_gemv_part<<<dim3(8, 2, 8), dim3(256), 0, stream>>>(kv, Wk, Wv, gpart);
  k_gemv_reduce<<<dim3(64), dim3(256), 0, stream>>>(gpart, knew, vnew);
  k_prep_kv<<<dim3(32768), dim3(256), 0, stream>>>(cache, knew, vnew, cost, sint,
                                                   cache_out, Kro, Vbf);
  k_transpose_w<<<dim3(64, 64, 2), dim3(256), 0, stream>>>(Wq, Wo, WqT, WoT);
  k_q_bf16<<<dim3(8192), dim3(256), 0, stream>>>(q, qbf);
  k_gemm<2><<<dim3(16, 32), dim3(256), 0, stream>>>(qbf, WqT, Qro, cost, sint,
                                                    B_ * LQ, F_, F_);
  k_attn<<<dim3(64, 8), dim3(256), 0, stream>>>(Qro, Kro, Vbf, attno);
  k_gemm<0><<<dim3(16, 32), dim3(256), 0, stream>>>(attno, WoT, logits, nullptr, nullptr,
                                                    B_ * LQ, F_, F_);
}

// Round 12
// 317.832 us; speedup vs baseline: 1.0150x; 1.0150x over previous
//
#include <hip/hip_runtime.h>

#define B_  4
#define LQ  1024
#define LC  2047
#define LK  2048
#define F_  2048
#define H_  16
#define DH  128
#define NT  (LK / 64)

typedef __attribute__((ext_vector_type(4))) float f32x4;
typedef __attribute__((ext_vector_type(8))) __bf16 bf16x8;
typedef __attribute__((ext_vector_type(8))) unsigned short u16x8;

#define GLD16(gp, lp)                                                          \
  __builtin_amdgcn_global_load_lds(                                            \
      (const __attribute__((address_space(1))) void*)(gp),                     \
      (__attribute__((address_space(3))) void*)(lp), 16, 0, 0)

__device__ __forceinline__ unsigned short f2bf(float f) {
  unsigned u = __float_as_uint(f);
  u += 0x7FFFu + ((u >> 16) & 1u);
  return (unsigned short)(u >> 16);
}
__device__ __forceinline__ float bf2f(unsigned short u) {
  return __uint_as_float((unsigned)u << 16);
}
// pack two f32 -> two truncated bf16 in one u32 (lo = a, hi = b)
__device__ __forceinline__ unsigned pack_bf2(float a, float b) {
  return (__float_as_uint(b) & 0xffff0000u) | (__float_as_uint(a) >> 16);
}

// ---------------- cos/sin table: [pos 0..2047][j 0..63] ----------------
__global__ void k_tables(float* __restrict__ cost, float* __restrict__ sint) {
  int idx = blockIdx.x * 256 + threadIdx.x;   // 2048*64 entries
  int pos = idx >> 6, j = idx & 63;
  float theta = powf(1000.0f, -(float)j / 64.0f);
  float a = (float)pos * theta;
  cost[idx] = cosf(a);
  sint[idx] = sinf(a);
}

// ------- key_new/val_new partials: grid (8 colblk, 2 kv, 8 kchunk) ------
__global__ void k_gemv_part(const float* __restrict__ kv, const float* __restrict__ Wk,
                            const float* __restrict__ Wv, float* __restrict__ part) {
  __shared__ float kvs[4][256];
  int tid = threadIdx.x, z = blockIdx.z;
#pragma unroll
  for (int b = 0; b < 4; ++b) kvs[b][tid] = kv[b * F_ + z * 256 + tid];
  __syncthreads();
  const float* W = blockIdx.y ? Wv : Wk;
  int col = blockIdx.x * 256 + tid;
  float a0 = 0.f, a1 = 0.f, a2 = 0.f, a3 = 0.f;
  for (int k = 0; k < 256; ++k) {
    float w = W[(size_t)(z * 256 + k) * F_ + col];
    a0 = fmaf(kvs[0][k], w, a0);
    a1 = fmaf(kvs[1][k], w, a1);
    a2 = fmaf(kvs[2][k], w, a2);
    a3 = fmaf(kvs[3][k], w, a3);
  }
  float* o = part + (size_t)(blockIdx.y * 8 + z) * 8192;
  o[col] = a0; o[2048 + col] = a1; o[4096 + col] = a2; o[6144 + col] = a3;
}

// ------- fused: cache copy-out + append (inline 8-way partial reduce),
//         build RoPE'd K (bf16) + V (bf16)
__global__ void k_prep_kv(const float* __restrict__ cache, const float* __restrict__ gpart,
                          const float* __restrict__ cost, const float* __restrict__ sint,
                          float* __restrict__ cache_out,
                          unsigned short* __restrict__ Kr, unsigned short* __restrict__ Vb) {
  int t = blockIdx.x * 256 + threadIdx.x;   // 4*2048*16*64 = 2^23 threads
  int j = t & 63, h = (t >> 6) & 15, pos = (t >> 10) & 2047, b = t >> 21;
  int f = h * DH + j;
  float k1, v1, k2, v2;
  if (pos < LC) {
    const float* p = cache + ((size_t)(b * LC + pos) * F_ + f) * 2;
    float2 x = *(const float2*)p;
    float2 y = *(const float2*)(p + 128);     // f + 64
    k1 = x.x; v1 = x.y; k2 = y.x; v2 = y.y;
  } else {
    // pos == LC: new token -> reduce the 8 k-chunk partials inline
    float s0 = 0.f, s1 = 0.f, s2 = 0.f, s3 = 0.f;
#pragma unroll
    for (int z = 0; z < 8; ++z) {
      const float* gk = gpart + (size_t)z * 8192 + b * 2048;
      const float* gv = gpart + (size_t)(8 + z) * 8192 + b * 2048;
      s0 += gk[f]; s1 += gk[f + 64];
      s2 += gv[f]; s3 += gv[f + 64];
    }
    k1 = s0; k2 = s1; v1 = s2; v2 = s3;
  }
  float* o = cache_out + ((size_t)(b * LK + pos) * F_ + f) * 2;
  *(float2*)o = make_float2(k1, v1);
  *(float2*)(o + 128) = make_float2(k2, v2);
  float c = cost[pos * 64 + j], s = sint[pos * 64 + j];
  size_t kb = ((size_t)(b * H_ + h) * LK + pos) * DH + j;
  Kr[kb]      = f2bf(k1 * c - k2 * s);
  Kr[kb + 64] = f2bf(k2 * c + k1 * s);
  Vb[kb]      = f2bf(v1);
  Vb[kb + 64] = f2bf(v2);
}

// ------- W [K][N] f32 -> Wt [N][K] bf16, both weights in one launch -----
__global__ void k_transpose_w(const float* __restrict__ Wq, const float* __restrict__ Wo,
                              unsigned short* __restrict__ WqT, unsigned short* __restrict__ WoT) {
  __shared__ float tile[32][33];
  const float* W = blockIdx.z ? Wo : Wq;
  unsigned short* Wt = blockIdx.z ? WoT : WqT;
  int n0 = blockIdx.x * 32, k0 = blockIdx.y * 32;
  int tx = threadIdx.x & 31, ty = threadIdx.x >> 5;
#pragma unroll
  for (int p = 0; p < 4; ++p)
    tile[ty + p * 8][tx] = W[(size_t)(k0 + ty + p * 8) * F_ + n0 + tx];
  __syncthreads();
#pragma unroll
  for (int p = 0; p < 4; ++p)
    Wt[(size_t)(n0 + ty + p * 8) * F_ + k0 + tx] = f2bf(tile[tx][ty + p * 8]);
}

// ---------------- f32 -> bf16 elementwise (q) ---------------------------
__global__ void k_q_bf16(const float* __restrict__ x, unsigned short* __restrict__ y) {
  int t = blockIdx.x * 256 + threadIdx.x;
  float4 v = ((const float4*)x)[t];
  ushort4 o;
  o.x = f2bf(v.x); o.y = f2bf(v.y); o.z = f2bf(v.z); o.w = f2bf(v.w);
  ((ushort4*)y)[t] = o;
}

// --------- bf16 MFMA GEMM (m97 structure): C = A[M][K] * Bt[N][K]^T -----
// MODE 0: plain f32 C.  MODE 2: fused RoPE epilogue (N-tile == head dim).
template <int MODE>
__launch_bounds__(256)
__global__ void k_gemm(const unsigned short* __restrict__ A, const unsigned short* __restrict__ Bt,
                       void* __restrict__ Cv, const float* __restrict__ cost,
                       const float* __restrict__ sint, int M, int N, int K) {
  __shared__ __align__(16) unsigned short SMEM[16640];   // As|Bs (16KB); reused as X (33KB)
  unsigned short* As = SMEM;
  unsigned short* Bs = SMEM + 4096;
  int tid = threadIdx.x, wid = tid >> 6, l = tid & 63;
  int wm = wid >> 1, wn = wid & 1;
  int lr = l & 15, lg = l >> 4;
  int m0 = blockIdx.y * 128, n0 = blockIdx.x * 128;
  int row0 = tid >> 2, ch = tid & 3;
  const unsigned short* ga0 = A  + (size_t)(m0 + row0) * K + ch * 8;
  const unsigned short* ga1 = A  + (size_t)(m0 + row0 + 64) * K + ch * 8;
  const unsigned short* gb0 = Bt + (size_t)(n0 + row0) * K + ch * 8;
  const unsigned short* gb1 = Bt + (size_t)(n0 + row0 + 64) * K + ch * 8;
  f32x4 acc[4][4];
#pragma unroll
  for (int i = 0; i < 4; ++i)
#pragma unroll
    for (int j = 0; j < 4; ++j) acc[i][j] = (f32x4){0.f, 0.f, 0.f, 0.f};

  for (int kt = 0; kt < K; kt += 32) {
    __syncthreads();
    GLD16(ga0 + kt, As + tid * 8);
    GLD16(ga1 + kt, As + (tid + 256) * 8);
    GLD16(gb0 + kt, Bs + tid * 8);
    GLD16(gb1 + kt, Bs + (tid + 256) * 8);
    __syncthreads();
    bf16x8 af[4], bfr[4];
#pragma unroll
    for (int i = 0; i < 4; ++i) {
      af[i]  = *(const bf16x8*)&As[(wm * 64 + i * 16 + lr) * 32 + lg * 8];
      bfr[i] = *(const bf16x8*)&Bs[(wn * 64 + i * 16 + lr) * 32 + lg * 8];
    }
    __builtin_amdgcn_s_setprio(1);
#pragma unroll
    for (int mi = 0; mi < 4; ++mi)
#pragma unroll
      for (int ni = 0; ni < 4; ++ni)
        acc[mi][ni] = __builtin_amdgcn_mfma_f32_16x16x32_bf16(af[mi], bfr[ni], acc[mi][ni], 0, 0, 0);
    __builtin_amdgcn_s_setprio(0);
  }

  if (MODE == 0) {
#pragma unroll
    for (int mi = 0; mi < 4; ++mi)
#pragma unroll
      for (int ni = 0; ni < 4; ++ni) {
        int row = m0 + wm * 64 + mi * 16 + lg * 4;
        int col = n0 + wn * 64 + ni * 16 + lr;
#pragma unroll
        for (int r = 0; r < 4; ++r)
          ((float*)Cv)[(size_t)(row + r) * N + col] = acc[mi][ni][r];
      }
  } else {
    // ---- fused RoPE epilogue ----
    unsigned short* X = SMEM;                 // [128][130] bf16 exchange tile
    __syncthreads();                          // all waves done with As/Bs
#pragma unroll
    for (int mi = 0; mi < 4; ++mi)
#pragma unroll
      for (int ni = 0; ni < 4; ++ni) {
        int lrow = wm * 64 + mi * 16 + lg * 4;
        int col = wn * 64 + ni * 16 + lr;
#pragma unroll
        for (int r = 0; r < 4; ++r)
          X[(lrow + r) * 130 + col] = f2bf(acc[mi][ni][r]);
      }
    __syncthreads();
    int h = blockIdx.x;
    const float scale = 0.12751743343788055f;  // (1/sqrt(128)) * log2(e)
    unsigned short* Q = (unsigned short*)Cv;
#pragma unroll
    for (int mi = 0; mi < 4; ++mi) {
      int lrow0 = wm * 64 + mi * 16 + lg * 4;
#pragma unroll
      for (int r = 0; r < 4; ++r) {
        int lrow = lrow0 + r;
        int grow = m0 + lrow;
        int qi = grow & 1023, b = grow >> 10;
        size_t obase = ((size_t)(b * H_ + h) * LQ + qi) * DH;
#pragma unroll
        for (int ni = 0; ni < 4; ++ni) {
          int col = wn * 64 + ni * 16 + lr;
          int jj = col & 63;
          float c = cost[qi * 64 + jj], s = sint[qi * 64 + jj];
          float a = acc[mi][ni][r];
          float a2 = bf2f(X[lrow * 130 + (col ^ 64)]);
          float o = (col < 64) ? (a * c - a2 * s) : (a * c + a2 * s);
          Q[obase + col] = f2bf(o * scale);
        }
      }
    }
  }
}

// --- flash attention: 4 waves x 32 q-rows, BK=64, rotated pipeline ------
// Key-permuted P/V layout: pi(k) = 2(k&15) + ((k>>4)&1) + (k&32) applied to
// BOTH P's and V's key axis (PV invariant). Thread's 4 P-values become two
// adjacent pairs -> packed u32 ds_writes (no same-word half conflicts).
__launch_bounds__(256, 2)
__global__ void k_attn(const unsigned short* __restrict__ Qr, const unsigned short* __restrict__ Kr,
                       const unsigned short* __restrict__ Vb, unsigned short* __restrict__ Oo) {
  __shared__ __align__(16) unsigned short KsB[2][64 * 128]; // linear, chunk-swizzled
  __shared__ __align__(16) unsigned short Vt[128][72];      // V transposed, permuted+swizzled keys
  __shared__ __align__(16) unsigned short Pb[4][32][72];    // per-wave P [q][permuted key]
  int tid = threadIdx.x, wid = tid >> 6, l = tid & 63;
  int lr = l & 15, lg = l >> 4;
  int bh = blockIdx.x, q0 = blockIdx.y * 128 + wid * 32;    // grid (64,8): same-bh -> same XCD
  const unsigned short* Qb = Qr + ((size_t)bh * LQ + q0) * DH;
  const unsigned short* Kb = Kr + (size_t)bh * LK * DH;
  const unsigned short* Vp = Vb + (size_t)bh * LK * DH;

  bf16x8 qf[2][4];
#pragma unroll
  for (int s = 0; s < 2; ++s)
#pragma unroll
    for (int c = 0; c < 4; ++c)
      qf[s][c] = *(const bf16x8*)(Qb + (size_t)(s * 16 + lr) * DH + c * 32 + lg * 8);

  // K staging: 4 chunks/thread; stored chunk c of row holds global chunk c^(row&15)
  int gkoff[4], lkoff[4];
#pragma unroll
  for (int p = 0; p < 4; ++p) {
    int g = tid + p * 256, row = g >> 4, cc = g & 15;
    gkoff[p] = row * DH + (cc ^ (row & 15)) * 8;
    lkoff[p] = g * 8;
  }

  f32x4 oacc[2][8];
#pragma unroll
  for (int s = 0; s < 2; ++s)
#pragma unroll
    for (int i = 0; i < 8; ++i) oacc[s][i] = (f32x4){0.f, 0.f, 0.f, 0.f};
  float mrun[2][4] = {{-1e30f, -1e30f, -1e30f, -1e30f}, {-1e30f, -1e30f, -1e30f, -1e30f}};
  float lpart[2][4] = {{0.f, 0.f, 0.f, 0.f}, {0.f, 0.f, 0.f, 0.f}};

  int kp = tid >> 4, cg = tid & 15;   // kp: base key 0..15; cg: 16B d-chunk

  // prologue: K(0) -> buf0; V(0) -> regs (keys kp, kp+16, kp+32, kp+48)
#pragma unroll
  for (int p = 0; p < 4; ++p) GLD16(Kb + gkoff[p], &KsB[0][lkoff[p]]);
  const unsigned short* vs0 = Vp + (size_t)kp * DH + cg * 8;
  u16x8 v00 = *(const u16x8*)(vs0);
  u16x8 v01 = *(const u16x8*)(vs0 + 16 * DH);
  u16x8 v10 = *(const u16x8*)(vs0 + 32 * DH);
  u16x8 v11 = *(const u16x8*)(vs0 + 48 * DH);

  for (int kt = 0; kt < NT; ++kt) {
    int cur = kt & 1;
    // everything needed this tile was issued a full tile ago -> free wait
    asm volatile("s_waitcnt vmcnt(0)" ::: "memory");
    __builtin_amdgcn_sched_barrier(0);
    __builtin_amdgcn_s_barrier();      // A: all waves done reading prev tile
    __builtin_amdgcn_sched_barrier(0);

    // V(t) ds_writes: permuted pair j holds original keys (j, j+16)|(j+16,j+32)
#pragma unroll
    for (int pp = 0; pp < 2; ++pp) {
      int j = kp + pp * 16;
      int kks = j ^ ((cg & 7) << 2);
      u16x8 a = pp ? v10 : v00, b2 = pp ? v11 : v01;
#pragma unroll
      for (int e = 0; e < 8; ++e) {
        unsigned pack = (unsigned)a[e] | ((unsigned)b2[e] << 16);
        *(unsigned*)&Vt[cg * 8 + e][kks * 2] = pack;
      }
    }
    // prefetch K(t+1) into alt buffer (dummy tile-0 prefetch on last iter)
    {
      const unsigned short* Kn = Kb + (size_t)((kt + 1 < NT) ? (kt + 1) * 64 * DH : 0);
#pragma unroll
      for (int p = 0; p < 4; ++p) GLD16(Kn + gkoff[p], &KsB[cur ^ 1][lkoff[p]]);
    }
    // prefetch V(t+1) into regs (dummy re-read of t on last iter)
    {
      int tn = (kt + 1 < NT) ? kt + 1 : kt;
      const unsigned short* vn = Vp + (size_t)(tn * 64 + kp) * DH + cg * 8;
      v00 = *(const u16x8*)(vn);
      v01 = *(const u16x8*)(vn + 16 * DH);
      v10 = *(const u16x8*)(vn + 32 * DH);
      v11 = *(const u16x8*)(vn + 48 * DH);
    }
    // own Vt writes done; cross-wave visibility via barrier B
    asm volatile("s_waitcnt lgkmcnt(0)" ::: "memory");
    __builtin_amdgcn_sched_barrier(0);
    __builtin_amdgcn_s_barrier();      // B: K(t) + Vt(t) ready for all
    __builtin_amdgcn_sched_barrier(0);

    // S = Q K^T : K fragment loaded once, used by both subtiles
    const unsigned short* Kcur = KsB[cur];
    f32x4 sf[2][4];
    __builtin_amdgcn_s_setprio(1);
#pragma unroll
    for (int ct = 0; ct < 4; ++ct) {
      f32x4 s0 = (f32x4){0.f, 0.f, 0.f, 0.f};
      f32x4 s1 = (f32x4){0.f, 0.f, 0.f, 0.f};
#pragma unroll
      for (int ck = 0; ck < 4; ++ck) {
        bf16x8 kf = *(const bf16x8*)&Kcur[(ct * 16 + lr) * 128 + (((ck * 4 + lg) ^ lr) << 3)];
        s0 = __builtin_amdgcn_mfma_f32_16x16x32_bf16(qf[0][ck], kf, s0, 0, 0, 0);
        s1 = __builtin_amdgcn_mfma_f32_16x16x32_bf16(qf[1][ck], kf, s1, 0, 0, 0);
      }
      sf[0][ct] = s0; sf[1][ct] = s1;
    }
    __builtin_amdgcn_s_setprio(0);

    // defer-max online softmax (both subtiles share the skip test)
    float pmax[2][4];
    bool allok = true;
#pragma unroll
    for (int s = 0; s < 2; ++s)
#pragma unroll
      for (int r = 0; r < 4; ++r) {
        pmax[s][r] = fmaxf(fmaxf(sf[s][0][r], sf[s][1][r]), fmaxf(sf[s][2][r], sf[s][3][r]));
        allok = allok && (pmax[s][r] - mrun[s][r] <= 8.0f);
      }
    if (!__all(allok)) {
#pragma unroll
      for (int s = 0; s < 2; ++s)
#pragma unroll
        for (int r = 0; r < 4; ++r) {
          float m = pmax[s][r];
#pragma unroll
          for (int off = 1; off < 16; off <<= 1) m = fmaxf(m, __shfl_xor(m, off));
          float mnew = fmaxf(mrun[s][r], m);
          float scl = exp2f(mrun[s][r] - mnew);
          lpart[s][r] *= scl;
#pragma unroll
          for (int dt = 0; dt < 8; ++dt) oacc[s][dt][r] *= scl;
          mrun[s][r] = mnew;
        }
    }
    // P stores: two packed u32 per (s,r) at permuted cols lr and 16+lr
#pragma unroll
    for (int s = 0; s < 2; ++s)
#pragma unroll
      for (int r = 0; r < 4; ++r) {
        float p0 = exp2f(sf[s][0][r] - mrun[s][r]);
        float p1 = exp2f(sf[s][1][r] - mrun[s][r]);
        float p2 = exp2f(sf[s][2][r] - mrun[s][r]);
        float p3 = exp2f(sf[s][3][r] - mrun[s][r]);
        lpart[s][r] += (p0 + p1) + (p2 + p3);
        unsigned* row = (unsigned*)&Pb[wid][s * 16 + lg * 4 + r][0];
        row[lr]      = pack_bf2(p0, p1);
        row[16 + lr] = pack_bf2(p2, p3);
      }

    // O += P V : V fragment loaded once, used by both subtiles
    // (compiler inserts lgkmcnt for the wave-private Pb write->read dep)
    bf16x8 pf00 = *(const bf16x8*)&Pb[wid][lr][lg * 8];
    bf16x8 pf01 = *(const bf16x8*)&Pb[wid][lr][32 + lg * 8];
    bf16x8 pf10 = *(const bf16x8*)&Pb[wid][16 + lr][lg * 8];
    bf16x8 pf11 = *(const bf16x8*)&Pb[wid][16 + lr][32 + lg * 8];
    __builtin_amdgcn_s_setprio(1);
#pragma unroll
    for (int dt = 0; dt < 8; ++dt) {
      int d = dt * 16 + lr;
      int x = (d >> 3) & 7;
      bf16x8 v0 = *(const bf16x8*)&Vt[d][(lg ^ x) << 3];
      bf16x8 v1 = *(const bf16x8*)&Vt[d][((4 + lg) ^ x) << 3];
      oacc[0][dt] = __builtin_amdgcn_mfma_f32_16x16x32_bf16(pf00, v0, oacc[0][dt], 0, 0, 0);
      oacc[0][dt] = __builtin_amdgcn_mfma_f32_16x16x32_bf16(pf01, v1, oacc[0][dt], 0, 0, 0);
      oacc[1][dt] = __builtin_amdgcn_mfma_f32_16x16x32_bf16(pf10, v0, oacc[1][dt], 0, 0, 0);
      oacc[1][dt] = __builtin_amdgcn_mfma_f32_16x16x32_bf16(pf11, v1, oacc[1][dt], 0, 0, 0);
    }
    __builtin_amdgcn_s_setprio(0);
  }

  int b = bh >> 4, h = bh & 15;
#pragma unroll
  for (int s = 0; s < 2; ++s)
#pragma unroll
    for (int r = 0; r < 4; ++r) {
      float sum = lpart[s][r];
#pragma unroll
      for (int off = 1; off < 16; off <<= 1) sum += __shfl_xor(sum, off);
      float inv = 1.0f / sum;
      int qrow = q0 + s * 16 + lg * 4 + r;
      size_t base = ((size_t)(b * LQ + qrow)) * F_ + h * DH;
#pragma unroll
      for (int dt = 0; dt < 8; ++dt)
        Oo[base + dt * 16 + lr] = f2bf(oacc[s][dt][r] * inv);
    }
}

extern "C" void kernel_launch(void* const* d_in, const int* in_sizes, int n_in,
                              void* d_out, int out_size, void* d_ws, size_t ws_size,
                              hipStream_t stream) {
  const float* kv    = (const float*)d_in[0];
  const float* q     = (const float*)d_in[1];
  const float* cache = (const float*)d_in[2];
  const float* Wq    = (const float*)d_in[3];
  const float* Wk    = (const float*)d_in[4];
  const float* Wv    = (const float*)d_in[5];
  const float* Wo    = (const float*)d_in[6];

  float* logits    = (float*)d_out;
  float* cache_out = logits + (size_t)B_ * LQ * F_;

  char* ws = (char*)d_ws;
  float* cost          = (float*)(ws);                       // 512 KB
  float* sint          = (float*)(ws + 524288);              // 512 KB
  float* gpart         = (float*)(ws + 1114112);             // 512 KB
  unsigned short* WqT  = (unsigned short*)(ws + 1638400);    // 8 MB
  unsigned short* WoT  = (unsigned short*)(ws + 10027008);   // 8 MB
  unsigned short* qbf  = (unsigned short*)(ws + 18415616);   // 16 MB
  unsigned short* Qro  = (unsigned short*)(ws + 35192832);   // 16 MB
  unsigned short* Kro  = (unsigned short*)(ws + 51970048);   // 32 MB
  unsigned short* Vbf  = (unsigned short*)(ws + 85524480);   // 32 MB
  unsigned short* attno = (unsigned short*)(ws + 127467520); // 16 MB

  k_tables<<<dim3(512), dim3(256), 0, stream>>>(cost, sint);
  k_gemv_part<<<dim3(8, 2, 8), dim3(256), 0, stream>>>(kv, Wk, Wv, gpart);
  k_prep_kv<<<dim3(32768), dim3(256), 0, stream>>>(cache, gpart, cost, sint,
                                                   cache_out, Kro, Vbf);
  k_transpose_w<<<dim3(64, 64, 2), dim3(256), 0, stream>>>(Wq, Wo, WqT, WoT);
  k_q_bf16<<<dim3(8192), dim3(256), 0, stream>>>(q, qbf);
  k_gemm<2><<<dim3(16, 32), dim3(256), 0, stream>>>(qbf, WqT, Qro, cost, sint,
                                                    B_ * LQ, F_, F_);
  k_attn<<<dim3(64, 8), dim3(256), 0, stream>>>(Qro, Kro, Vbf, attno);
  k_gemm<0><<<dim3(16, 32), dim3(256), 0, stream>>>(attno, WoT, logits, nullptr, nullptr,
                                                    B_ * LQ, F_, F_);
}